// Round 18
// baseline (273.905 us; speedup 1.0000x reference)
//
#include <hip/hip_runtime.h>
#include <hip/hip_bf16.h>
#include <math.h>

#define N_ROWS 4096
#define DIM    512
#define M_ROWS 8192
// sim GEMM: 128x128 tiles, 4 waves (2x2 of 64x64), BK=32, WAVE-PRIVATE LDS,
// ZERO barriers (round-16 best-known: sim 69.3 us, absmax 0) + round-12's
// PROVEN fused loss finale (atomic done-counter + threadfence, passed
// absmax 0 twice at this exact grid size). 3 dispatches -> 2.
#define BK     32
#define NB     2080          // 64*65/2 triangular tiles (2080 % 8 == 0)
#define NSTEP  16            // 512 / 32
// exp(sim/0.1) = exp2(sim * 10*log2(e))
#define EXP_SCALE 14.4269504088896340736f

typedef unsigned short ushort_t;
typedef __attribute__((ext_vector_type(8))) short short8;
typedef __attribute__((ext_vector_type(4))) float f32x4;

__device__ __forceinline__ ushort_t f2bf(float x) {
  unsigned int bits = __float_as_uint(x);
  unsigned int lsb = (bits >> 16) & 1u;
  bits += 0x7fffu + lsb;
  return (ushort_t)(bits >> 16);
}

__device__ __forceinline__ void store4bf(ushort_t* p, float4 v, float s) {
  union { ushort_t u[4]; uint2 d; } pk;
  pk.u[0] = f2bf(v.x * s);
  pk.u[1] = f2bf(v.y * s);
  pk.u[2] = f2bf(v.z * s);
  pk.u[3] = f2bf(v.w * s);
  *(uint2*)p = pk.d;
}

// async global -> LDS, 16 B/lane (lds dest = wave-uniform base + lane*16)
__device__ __forceinline__ void async16(const ushort_t* g, ushort_t* l) {
  __builtin_amdgcn_global_load_lds(
      (const __attribute__((address_space(1))) void*)g,
      (__attribute__((address_space(3))) void*)l,
      16, 0, 0);
}

// ---------------------------------------------------------------------------
// Kernel 1: per-row L2 normalize; 256-thread blocks, one wave per row-pair.
// Also zeroes denom[] and the done-counter. (Verified structure.)
// ---------------------------------------------------------------------------
__global__ __launch_bounds__(256) void norm_kernel(
    const float* __restrict__ ei, const float* __restrict__ ej,
    ushort_t* __restrict__ reps, float* __restrict__ pos,
    float* __restrict__ denom, unsigned int* __restrict__ ctr) {
  int wave = threadIdx.x >> 6;
  int lane = threadIdx.x & 63;
  int b = blockIdx.x * 4 + wave;
  if (blockIdx.x == 0 && threadIdx.x == 0) *ctr = 0u;
  if (lane == 0) {
    denom[b] = 0.0f;
    denom[b + N_ROWS] = 0.0f;
  }
  const float4* pi = (const float4*)(ei + (size_t)b * DIM);
  const float4* pj = (const float4*)(ej + (size_t)b * DIM);
  float4 a0 = pi[lane];
  float4 a1 = pi[lane + 64];
  float4 b0 = pj[lane];
  float4 b1 = pj[lane + 64];

  float si = a0.x*a0.x + a0.y*a0.y + a0.z*a0.z + a0.w*a0.w
           + a1.x*a1.x + a1.y*a1.y + a1.z*a1.z + a1.w*a1.w;
  float sj = b0.x*b0.x + b0.y*b0.y + b0.z*b0.z + b0.w*b0.w
           + b1.x*b1.x + b1.y*b1.y + b1.z*b1.z + b1.w*b1.w;
  float dp = a0.x*b0.x + a0.y*b0.y + a0.z*b0.z + a0.w*b0.w
           + a1.x*b1.x + a1.y*b1.y + a1.z*b1.z + a1.w*b1.w;

#pragma unroll
  for (int m = 32; m >= 1; m >>= 1) {
    si += __shfl_xor(si, m, 64);
    sj += __shfl_xor(sj, m, 64);
    dp += __shfl_xor(dp, m, 64);
  }
  float ii = 1.0f / fmaxf(sqrtf(si), 1e-12f);
  float ij = 1.0f / fmaxf(sqrtf(sj), 1e-12f);
  if (lane == 0) pos[b] = dp * ii * ij;

  ushort_t* ri = reps + (size_t)b * DIM;
  ushort_t* rj = reps + (size_t)(b + N_ROWS) * DIM;
  store4bf(ri + lane * 4,       a0, ii);
  store4bf(ri + 256 + lane * 4, a1, ii);
  store4bf(rj + lane * 4,       b0, ij);
  store4bf(rj + 256 + lane * 4, b1, ij);
}

// ---------------------------------------------------------------------------
// Kernel 2: 128x128-tile fused sim-GEMM + exp + masked row/col reduction
// + fused loss finale (round-12 proven pattern).
// BARRIER-FREE main loop: each wave owns a private 16 KB LDS slice
// (2 dbuf x (4 KB A + 4 KB B)) and stages its own 64-row panels.
//  RAW: loop-top issues 8 stage loads for buf[nxt], then vmcnt(8) -> the 8
//       issued LAST iteration (into buf[cur]) are confirmed landed.
//  WAR: ds_reads retire (lgkmcnt) before consuming MFMAs, which precede the
//       next stage of the same buffer in program order.
// Keeps: super-tile blob order + chunked XCD remap, both-sides XOR swizzle.
// Finale: threadfence (release) -> atomicAdd ctr -> last block re-reads
// denom (acquire fence) and computes the loss. Passed absmax 0 in r12/r13.
// ---------------------------------------------------------------------------
__global__ __launch_bounds__(256) void sim_kernel(
    const ushort_t* __restrict__ reps, float* __restrict__ denom,
    const float* __restrict__ pos, float* __restrict__ out,
    unsigned int* __restrict__ ctr) {
  // chunked XCD remap: XCD x owns logical ids [x*260, (x+1)*260)
  int id = blockIdx.x;
  id = (id & 7) * (NB / 8) + (id >> 3);

  // super-tile blob decode: 4x4 super grid (16x16 tiles each), sj-major,
  // si<=sj; diag super = 136 tiles (16x16 triangle), off-diag = 256.
  int bi, bj;
  {
    int rem = id, Si = 0, Sj = 0, fnd = 0;
    for (int s_j = 0; s_j < 4 && !fnd; ++s_j)
      for (int s_i = 0; s_i <= s_j && !fnd; ++s_i) {
        int sz = (s_i == s_j) ? 136 : 256;
        if (rem < sz) { Si = s_i; Sj = s_j; fnd = 1; }
        else rem -= sz;
      }
    if (Si == Sj) {
      int tj = 0;
      while ((tj + 1) * (tj + 2) / 2 <= rem) ++tj;   // tj <= 15
      int ti = rem - tj * (tj + 1) / 2;
      bi = Si * 16 + ti;
      bj = Sj * 16 + tj;
    } else {
      bi = Si * 16 + (rem & 15);
      bj = Sj * 16 + (rem >> 4);
    }
  }

  // wave-private LDS: [wave][dbuf][A(2048) | B(2048)] ushorts = 64 KB total
  __shared__ ushort_t Wl[4][2][4096];
  __shared__ float red[4];
  __shared__ int lastflag;

  int tid  = threadIdx.x;
  int wave = tid >> 6, lane = tid & 63;
  int wr = wave >> 1, wc = wave & 1;     // 2x2 wave grid, 64x64 each
  int quad = lane >> 4, l15 = lane & 15;

  // staging: this wave stages its own 64 A-rows (wr half) and 64 B-rows
  // (wc half); 4 async16 each (16 rows x 64 B = 1 KB per instr).
  // Source col pre-swizzled so linear LDS holds row r's slot s at
  // (s ^ ((r>>1)&3)) -- conflict-free ds_read_b128 (verified 0 conflicts).
  int srow  = lane >> 2;                               // row within 16-chunk
  int selem = ((lane & 3) ^ ((srow >> 1) & 3)) * 8;    // swizzled elem offset
  const ushort_t* gA0 = reps + (size_t)(bi * 128 + wr * 64 +  0 + srow) * DIM + selem;
  const ushort_t* gA1 = reps + (size_t)(bi * 128 + wr * 64 + 16 + srow) * DIM + selem;
  const ushort_t* gA2 = reps + (size_t)(bi * 128 + wr * 64 + 32 + srow) * DIM + selem;
  const ushort_t* gA3 = reps + (size_t)(bi * 128 + wr * 64 + 48 + srow) * DIM + selem;
  const ushort_t* gB0 = reps + (size_t)(bj * 128 + wc * 64 +  0 + srow) * DIM + selem;
  const ushort_t* gB1 = reps + (size_t)(bj * 128 + wc * 64 + 16 + srow) * DIM + selem;
  const ushort_t* gB2 = reps + (size_t)(bj * 128 + wc * 64 + 32 + srow) * DIM + selem;
  const ushort_t* gB3 = reps + (size_t)(bj * 128 + wc * 64 + 48 + srow) * DIM + selem;

#define STAGE_W(D, KOFF) do {                         \
    ushort_t* b_ = &Wl[wave][D][0];                   \
    async16(gA0 + (KOFF), b_);                        \
    async16(gA1 + (KOFF), b_ + 512);                  \
    async16(gA2 + (KOFF), b_ + 1024);                 \
    async16(gA3 + (KOFF), b_ + 1536);                 \
    async16(gB0 + (KOFF), b_ + 2048);                 \
    async16(gB1 + (KOFF), b_ + 2560);                 \
    async16(gB2 + (KOFF), b_ + 3072);                 \
    async16(gB3 + (KOFF), b_ + 3584);                 \
  } while (0)

  // fragment reads: row = t*16 + l15 within the wave's private 64-row panel
  int sqr = (quad ^ ((l15 >> 1) & 3)) * 8;

  f32x4 zero4 = {0.0f, 0.0f, 0.0f, 0.0f};
  f32x4 acc[4][4];
#pragma unroll
  for (int tr = 0; tr < 4; ++tr)
#pragma unroll
    for (int tc = 0; tc < 4; ++tc) acc[tr][tc] = zero4;

  // prologue: stage k-step 0 into buffer 0 (8 loads outstanding)
  STAGE_W(0, 0);

  for (int kk = 0; kk < NSTEP; ++kk) {
    int cur = kk & 1;

    if (kk + 1 < NSTEP) {
      STAGE_W(cur ^ 1, (kk + 1) * BK);                 // 8 new loads
      asm volatile("s_waitcnt vmcnt(8)" ::: "memory"); // prior 8 landed
    } else {
      asm volatile("s_waitcnt vmcnt(0)" ::: "memory"); // drain final buffer
    }
    // NO barrier: LDS slice is wave-private.

    const ushort_t* Ab = &Wl[wave][cur][0];
    const ushort_t* Bb = &Wl[wave][cur][2048];
    short8 aF[4], bF[4];
#pragma unroll
    for (int t = 0; t < 4; ++t) {
      aF[t] = *(const short8*)(Ab + (t * 16 + l15) * BK + sqr);
      bF[t] = *(const short8*)(Bb + (t * 16 + l15) * BK + sqr);
    }
    __builtin_amdgcn_s_setprio(1);
#pragma unroll
    for (int tr = 0; tr < 4; ++tr)
#pragma unroll
      for (int tc = 0; tc < 4; ++tc)
        acc[tr][tc] = __builtin_amdgcn_mfma_f32_16x16x32_bf16(
            aF[tr], bF[tc], acc[tr][tc], 0, 0, 0);
    __builtin_amdgcn_s_setprio(0);
    // NO barrier: WAR handled by program order + lgkmcnt retirement.
  }

  // ---- epilogue: e = exp(sim/T), mask diagonal, row + col sums ----
  // C layout per 16x16 frag: col = l15, row = quad*4 + r  [m89/m91]
  int rowg_base = bi * 128 + wr * 64;
  int colg_base = bj * 128 + wc * 64;

  f32x4 rsum[4];
  float csum[4] = {0.0f, 0.0f, 0.0f, 0.0f};
#pragma unroll
  for (int tr = 0; tr < 4; ++tr) rsum[tr] = zero4;

#pragma unroll
  for (int tr = 0; tr < 4; ++tr) {
    int rowg0 = rowg_base + tr * 16 + quad * 4;
#pragma unroll
    for (int tc = 0; tc < 4; ++tc) {
      int colg = colg_base + tc * 16 + l15;
      f32x4 a = acc[tr][tc];
      f32x4 e;
#pragma unroll
      for (int r = 0; r < 4; ++r) {
        float v = exp2f(a[r] * EXP_SCALE);
        e[r] = ((rowg0 + r) == colg) ? 0.0f : v;
      }
      rsum[tr] += e;
      csum[tc] += e[0] + e[1] + e[2] + e[3];
    }
  }

  // reduce row sums across the 16 lanes sharing `quad` (masks 1,2,4,8)
#pragma unroll
  for (int m = 1; m <= 8; m <<= 1)
#pragma unroll
    for (int tr = 0; tr < 4; ++tr)
#pragma unroll
      for (int r = 0; r < 4; ++r)
        rsum[tr][r] += __shfl_xor(rsum[tr][r], m, 64);

  if (l15 == 0) {
#pragma unroll
    for (int tr = 0; tr < 4; ++tr)
#pragma unroll
      for (int r = 0; r < 4; ++r)
        atomicAdd(&denom[rowg_base + tr * 16 + quad * 4 + r], rsum[tr][r]);
  }

  if (bi != bj) {
    // reduce col sums across quads (masks 16,32)
#pragma unroll
    for (int m = 16; m <= 32; m <<= 1)
#pragma unroll
      for (int tc = 0; tc < 4; ++tc)
        csum[tc] += __shfl_xor(csum[tc], m, 64);
    if (quad == 0) {
#pragma unroll
      for (int tc = 0; tc < 4; ++tc)
        atomicAdd(&denom[colg_base + tc * 16 + l15], csum[tc]);
    }
  }

  // ---- fused finale (round-12 proven): last block computes the loss ----
  __threadfence();   // release: our denom atomics visible before ctr bump
  if (tid == 0) lastflag = (atomicAdd(ctr, 1u) == (unsigned int)(NB - 1));
  __syncthreads();
  if (lastflag) {
    __threadfence();  // acquire: all blocks' denom atomics visible
    float p = 0.0f;
    for (int r = tid; r < M_ROWS; r += 256)
      p += logf(denom[r]) - pos[r & (N_ROWS - 1)] * 10.0f;
#pragma unroll
    for (int m = 32; m >= 1; m >>= 1) p += __shfl_xor(p, m, 64);
    if ((tid & 63) == 0) red[tid >> 6] = p;
    __syncthreads();
    if (tid == 0)
      out[0] = (red[0] + red[1] + red[2] + red[3]) * (1.0f / M_ROWS);
  }
}

extern "C" void kernel_launch(void* const* d_in, const int* in_sizes, int n_in,
                              void* d_out, int out_size, void* d_ws, size_t ws_size,
                              hipStream_t stream) {
  const float* ei = (const float*)d_in[0];
  const float* ej = (const float*)d_in[1];
  float* out = (float*)d_out;

  char* ws = (char*)d_ws;
  ushort_t* reps = (ushort_t*)ws;                                   // 8 MB bf16
  float* denom = (float*)(ws + (size_t)M_ROWS * DIM * 2);           // 32 KB
  float* pos = (float*)(ws + (size_t)M_ROWS * DIM * 2 + M_ROWS * 4);// 16 KB
  unsigned int* ctr = (unsigned int*)(ws + (size_t)M_ROWS * DIM * 2
                                       + M_ROWS * 4 + N_ROWS * 4);

  norm_kernel<<<N_ROWS / 4, 256, 0, stream>>>(ei, ej, reps, pos, denom, ctr);
  sim_kernel<<<NB, 256, 0, stream>>>(reps, denom, pos, out, ctr);
}